// Round 9
// baseline (375.838 us; speedup 1.0000x reference)
//
#include <hip/hip_runtime.h>
#include <stdint.h>

typedef __attribute__((ext_vector_type(4))) float f32x4;
typedef __attribute__((ext_vector_type(4))) int   i32x4;

__device__ __forceinline__ ushort f2bf(float f) {
  union { float f; uint32_t u; } v; v.f = f;
  uint32_t r = v.u + 0x7FFFu + ((v.u >> 16) & 1u);
  return (ushort)(r >> 16);
}
__device__ __forceinline__ float bf2f(ushort u) {
  union { uint32_t u; float f; } v; v.u = ((uint32_t)u) << 16; return v.f;
}
__device__ __forceinline__ void mfma_acc(f32x4& c, i32x4 a, i32x4 b) {
  asm volatile("v_mfma_f32_16x16x32_bf16 %0, %1, %2, %0" : "+v"(c) : "v"(a), "v"(b));
}
__device__ __forceinline__ void gload_lds16(const void* g, void* lds) {
  __builtin_amdgcn_global_load_lds(
      (const __attribute__((address_space(1))) void*)g,
      (__attribute__((address_space(3))) void*)lds, 16, 0, 0);
}

// ---------------- LN + bf16 cast:  xcat[row][1024], row = b*4352 + j ----------------
__global__ void __launch_bounds__(256) ln_kernel(
    const float* __restrict__ x, const float* __restrict__ lat,
    const float* __restrict__ gm, const float* __restrict__ bm,
    const float* __restrict__ gl, const float* __restrict__ bl,
    ushort* __restrict__ out) {
  int row = blockIdx.x;
  int b = row / 4352, j = row - b * 4352;
  const float *src, *g, *bi;
  if (j < 4096) { src = x + ((size_t)b * 4096 + j) * 1024; g = gm; bi = bm; }
  else          { src = lat + ((size_t)b * 256 + (j - 4096)) * 1024; g = gl; bi = bl; }
  int t = threadIdx.x;
  f32x4 v = ((const f32x4*)src)[t];
  float s = v.x + v.y + v.z + v.w;
  float q = v.x * v.x + v.y * v.y + v.z * v.z + v.w * v.w;
  #pragma unroll
  for (int o = 1; o < 64; o <<= 1) { s += __shfl_xor(s, o, 64); q += __shfl_xor(q, o, 64); }
  __shared__ float ss[4], sq[4];
  int w = t >> 6, l = t & 63;
  if (l == 0) { ss[w] = s; sq[w] = q; }
  __syncthreads();
  s = ss[0] + ss[1] + ss[2] + ss[3];
  q = sq[0] + sq[1] + sq[2] + sq[3];
  float mu = s * (1.f / 1024.f);
  float var = q * (1.f / 1024.f) - mu * mu;
  float rs = rsqrtf(var + 1e-5f);
  f32x4 gg = ((const f32x4*)g)[t], bb = ((const f32x4*)bi)[t];
  ushort4 o4;
  o4.x = f2bf((v.x - mu) * rs * gg.x + bb.x);
  o4.y = f2bf((v.y - mu) * rs * gg.y + bb.y);
  o4.z = f2bf((v.z - mu) * rs * gg.z + bb.z);
  o4.w = f2bf((v.w - mu) * rs * gg.w + bb.w);
  ((ushort4*)(out + (size_t)row * 1024))[t] = o4;
}

// ------------- merged weight transposes: Wkv, Wq, Wout -> [N][1024] bf16 -------------
__global__ void __launch_bounds__(256) tsplit3_kernel(
    const float* __restrict__ Wkv, const float* __restrict__ Wq, const float* __restrict__ Wout,
    ushort* __restrict__ wkvt, ushort* __restrict__ wqt, ushort* __restrict__ wot) {
  int bid = blockIdx.x;
  const float* W; ushort* out; int N, bid2;
  if (bid < 1024)      { W = Wkv;  out = wkvt; N = 2048; bid2 = bid; }
  else if (bid < 1536) { W = Wq;   out = wqt;  N = 1024; bid2 = bid - 1024; }
  else                 { W = Wout; out = wot;  N = 1024; bid2 = bid - 1536; }
  int ntn = N >> 6;
  int tk = bid2 / ntn, tn = bid2 - tk * ntn;
  int k0 = tk * 32, n0 = tn * 64;
  __shared__ float tile[32][65];
  int t = threadIdx.x;
  #pragma unroll
  for (int i = 0; i < 8; i++) {
    int idx = t + i * 256;              // 2048 = 32x64
    int k = idx >> 6, n = idx & 63;
    tile[k][n] = W[(size_t)(k0 + k) * N + n0 + n];
  }
  __syncthreads();
  #pragma unroll
  for (int i = 0; i < 8; i++) {
    int idx = t + i * 256;
    int n = idx >> 5, k = idx & 31;
    out[(size_t)(n0 + n) * 1024 + k0 + k] = f2bf(tile[k][n]);
  }
}

// ======= kv GEMM: 256x256, BK=64, 8 waves, 8-phase schedule (4 phases/K-tile) =======
// LDS: 2 slots x {A0,A1,B0,B1} half-tiles (16KB each; 128 rows x 64 bf16, row-XOR swizzle).
// Phase quadrants: P1=(M0,N0) P2=(M0,N1) P3=(M1,N1) P4=(M1,N0).
// Stages: P1: A1(T+1)->next slot; P2: B0(T+1)->next; P3: A0(T+2)->cur; P4: B1(T+2)->cur.
// Each half staged strictly after its last LDS read (barrier-separated). Boundary wait:
// vmcnt(4) once per K-tile (tightest dep: B0(T+1) staged P2, read T+1.P1); vmcnt(0) into T=15.
__global__ void __launch_bounds__(512, 2) gemm256_kv(
    const ushort* __restrict__ A, const ushort* __restrict__ Bw,
    ushort* __restrict__ okb, ushort* __restrict__ ovb) {
  int orig = blockIdx.x;
  int bx = (orig & 7) * 136 + (orig >> 3);       // 1088 = 8 XCD * 136
  int mt = bx >> 3, nt = bx & 7;
  int m0 = mt * 256, n0 = nt * 256;
  int t = threadIdx.x, w = t >> 6, l = t & 63, lg = l >> 4, lr = l & 15;
  int wr = w >> 2, wc = w & 3;                   // 2 x 4 waves; wave subtile 64x32 per quadrant

  __shared__ char smem[131072];                  // slot s at s*65536: A0 +0, A1 +16K, B0 +32K, B1 +48K

  auto stageH = [&](const ushort* src, int rowbase, int h, int T, char* dst) {
    #pragma unroll
    for (int i = 0; i < 2; i++) {
      int c = t + i * 512;                       // 1024 chunks of 16B = 128 rows x 128B
      int rl = c >> 3, j = c & 7;
      int sj = j ^ (rl & 7);                     // pre-swizzled source (involution)
      gload_lds16(src + ((size_t)(rowbase + h * 128 + rl) * 1024 + (size_t)T * 64 + sj * 8),
                  dst + c * 16);
    }
  };

  f32x4 acc[4][4][2];
  #pragma unroll
  for (int p = 0; p < 4; p++)
    #pragma unroll
    for (int i = 0; i < 4; i++)
      #pragma unroll
      for (int j = 0; j < 2; j++) acc[p][i][j] = (f32x4){0.f, 0.f, 0.f, 0.f};

  // prologue: slot0 fully + A0(1), B1(1) into slot1
  stageH(A,  m0, 0, 0, smem);
  stageH(A,  m0, 1, 0, smem + 16384);
  stageH(Bw, n0, 0, 0, smem + 32768);
  stageH(Bw, n0, 1, 0, smem + 49152);
  stageH(A,  m0, 0, 1, smem + 65536);
  stageH(Bw, n0, 1, 1, smem + 65536 + 49152);
  asm volatile("s_waitcnt vmcnt(4)" ::: "memory");
  __builtin_amdgcn_s_barrier();

  const int arl = wr * 64 + lr;
  const int brl = wc * 32 + lr;
  const int kcol0 = lg * 16;

  for (int T = 0; T < 16; T++) {
    char* cs = smem + (T & 1) * 65536;
    char* ns = smem + ((T + 1) & 1) * 65536;
    i32x4 a[4][2], b[2][2];

    // ---- P1: quadrant (M0,N0): read A0 + B0, stage A1(T+1) ----
    #pragma unroll
    for (int mi = 0; mi < 4; mi++) {
      int rl = arl + mi * 16;
      #pragma unroll
      for (int kk = 0; kk < 2; kk++)
        a[mi][kk] = *(const i32x4*)(cs + rl * 128 + ((kk * 64 + kcol0) ^ ((rl & 7) << 4)));
    }
    #pragma unroll
    for (int nj = 0; nj < 2; nj++) {
      int rl = brl + nj * 16;
      #pragma unroll
      for (int kk = 0; kk < 2; kk++)
        b[nj][kk] = *(const i32x4*)(cs + 32768 + rl * 128 + ((kk * 64 + kcol0) ^ ((rl & 7) << 4)));
    }
    if (T + 1 < 16) stageH(A, m0, 1, T + 1, ns + 16384);
    __builtin_amdgcn_s_barrier();
    __builtin_amdgcn_s_setprio(1);
    #pragma unroll
    for (int mi = 0; mi < 4; mi++)
      #pragma unroll
      for (int nj = 0; nj < 2; nj++)
        #pragma unroll
        for (int kk = 0; kk < 2; kk++) mfma_acc(acc[0][mi][nj], a[mi][kk], b[nj][kk]);
    __builtin_amdgcn_s_setprio(0);
    __builtin_amdgcn_s_barrier();

    // ---- P2: quadrant (M0,N1): reuse a, read B1, stage B0(T+1) ----
    #pragma unroll
    for (int nj = 0; nj < 2; nj++) {
      int rl = brl + nj * 16;
      #pragma unroll
      for (int kk = 0; kk < 2; kk++)
        b[nj][kk] = *(const i32x4*)(cs + 49152 + rl * 128 + ((kk * 64 + kcol0) ^ ((rl & 7) << 4)));
    }
    if (T + 1 < 16) stageH(Bw, n0, 0, T + 1, ns + 32768);
    __builtin_amdgcn_s_barrier();
    __builtin_amdgcn_s_setprio(1);
    #pragma unroll
    for (int mi = 0; mi < 4; mi++)
      #pragma unroll
      for (int nj = 0; nj < 2; nj++)
        #pragma unroll
        for (int kk = 0; kk < 2; kk++) mfma_acc(acc[1][mi][nj], a[mi][kk], b[nj][kk]);
    __builtin_amdgcn_s_setprio(0);
    __builtin_amdgcn_s_barrier();

    // ---- P3: quadrant (M1,N1): read A1, reuse b, stage A0(T+2) into cur slot ----
    #pragma unroll
    for (int mi = 0; mi < 4; mi++) {
      int rl = arl + mi * 16;
      #pragma unroll
      for (int kk = 0; kk < 2; kk++)
        a[mi][kk] = *(const i32x4*)(cs + 16384 + rl * 128 + ((kk * 64 + kcol0) ^ ((rl & 7) << 4)));
    }
    if (T + 2 < 16) stageH(A, m0, 0, T + 2, cs);
    __builtin_amdgcn_s_barrier();
    __builtin_amdgcn_s_setprio(1);
    #pragma unroll
    for (int mi = 0; mi < 4; mi++)
      #pragma unroll
      for (int nj = 0; nj < 2; nj++)
        #pragma unroll
        for (int kk = 0; kk < 2; kk++) mfma_acc(acc[2][mi][nj], a[mi][kk], b[nj][kk]);
    __builtin_amdgcn_s_setprio(0);
    __builtin_amdgcn_s_barrier();

    // ---- P4: quadrant (M1,N0): reuse a, re-read B0, stage B1(T+2) into cur slot ----
    #pragma unroll
    for (int nj = 0; nj < 2; nj++) {
      int rl = brl + nj * 16;
      #pragma unroll
      for (int kk = 0; kk < 2; kk++)
        b[nj][kk] = *(const i32x4*)(cs + 32768 + rl * 128 + ((kk * 64 + kcol0) ^ ((rl & 7) << 4)));
    }
    if (T + 2 < 16) stageH(Bw, n0, 1, T + 2, cs + 49152);
    __builtin_amdgcn_s_barrier();
    __builtin_amdgcn_s_setprio(1);
    #pragma unroll
    for (int mi = 0; mi < 4; mi++)
      #pragma unroll
      for (int nj = 0; nj < 2; nj++)
        #pragma unroll
        for (int kk = 0; kk < 2; kk++) mfma_acc(acc[3][mi][nj], a[mi][kk], b[nj][kk]);
    __builtin_amdgcn_s_setprio(0);
    if (T < 14) asm volatile("s_waitcnt vmcnt(4)" ::: "memory");
    else        asm volatile("s_waitcnt vmcnt(0)" ::: "memory");
    __builtin_amdgcn_s_barrier();
  }

  // scatter epilogue: quadrant p -> rows qm*128, cols qn*128; k cols<1024 -> kbuf else vbuf
  const int qmt[4] = {0, 0, 1, 1};
  const int qnt[4] = {0, 1, 1, 0};
  #pragma unroll
  for (int p = 0; p < 4; p++) {
    #pragma unroll
    for (int mi = 0; mi < 4; mi++) {
      #pragma unroll
      for (int r = 0; r < 4; r++) {
        int row = m0 + qmt[p] * 128 + wr * 64 + mi * 16 + lg * 4 + r;
        int bb = row / 4352; int n = row - bb * 4352;
        size_t base = (size_t)bb * 4456448 + (size_t)n * 64;
        #pragma unroll
        for (int nj = 0; nj < 2; nj++) {
          int col = n0 + qnt[p] * 128 + wc * 32 + nj * 16 + lr;
          int cc = col & 1023; int h = cc >> 6; int d = cc & 63;
          ushort* dst = (col < 1024) ? okb : ovb;
          dst[base + (size_t)h * 278528 + d] = f2bf(acc[p][mi][nj][r]);
        }
      }
    }
  }
}

// ---------------- small NT GEMM 128x128xBK32 (q and out projections) ----------------
template<int MODE>
__global__ void __launch_bounds__(256, 2) gemm_nt(
    const ushort* __restrict__ A, const ushort* __restrict__ Bw,
    ushort* __restrict__ okb, float* __restrict__ of,
    int ntn, int Keff, int lda, int ldb) {
  int orig = blockIdx.x;
  int bx = ((orig & 7) * (gridDim.x >> 3)) + (orig >> 3);
  int m0 = (bx / ntn) * 128, n0 = (bx - (bx / ntn) * ntn) * 128;
  int t = threadIdx.x, w = t >> 6, l = t & 63, lg = l >> 4, lr = l & 15;
  int wr = w >> 1, wc = w & 1;
  __shared__ ushort As[128 * 32];
  __shared__ ushort Bs[128 * 32];
  f32x4 acc[4][4];
  #pragma unroll
  for (int i = 0; i < 4; i++)
    #pragma unroll
    for (int j = 0; j < 4; j++) acc[i][j] = (f32x4){0.f, 0.f, 0.f, 0.f};

  int nk = Keff >> 5;
  for (int kt = 0; kt < nk; kt++) {
    int ka = kt * 32;
    #pragma unroll
    for (int c2 = 0; c2 < 2; c2++) {
      int c = w * 2 + c2;
      int arow = m0 + c * 16 + (l >> 2);
      if (MODE == 1) arow = ((arow >> 8) * 4352) + 4096 + (arow & 255);
      gload_lds16(A + (size_t)arow * lda + ka + (l & 3) * 8, &As[c * 512]);
    }
    #pragma unroll
    for (int c2 = 0; c2 < 2; c2++) {
      int c = w * 2 + c2;
      int brow = n0 + c * 16 + (l >> 2);
      gload_lds16(Bw + (size_t)brow * ldb + ka + (l & 3) * 8, &Bs[c * 512]);
    }
    __syncthreads();
    i32x4 af[4], bf[4];
    #pragma unroll
    for (int mi = 0; mi < 4; mi++)
      af[mi] = *(const i32x4*)&As[(wr * 64 + mi * 16 + lr) * 32 + lg * 8];
    #pragma unroll
    for (int nj = 0; nj < 4; nj++)
      bf[nj] = *(const i32x4*)&Bs[(wc * 64 + nj * 16 + lr) * 32 + lg * 8];
    #pragma unroll
    for (int mi = 0; mi < 4; mi++)
      #pragma unroll
      for (int nj = 0; nj < 4; nj++) mfma_acc(acc[mi][nj], af[mi], bf[nj]);
    __syncthreads();
  }

  #pragma unroll
  for (int mi = 0; mi < 4; mi++) {
    #pragma unroll
    for (int r = 0; r < 4; r++) {
      int row = m0 + wr * 64 + mi * 16 + lg * 4 + r;
      if (MODE == 1) {
        int b = row >> 8; int n2 = row & 255;
        size_t base = (size_t)b * 262144 + (size_t)n2 * 64;
        #pragma unroll
        for (int nj = 0; nj < 4; nj++) {
          int col = n0 + wc * 64 + nj * 16 + lr;
          int h = col >> 6; int d = col & 63;
          // scale = (1/8)/ln2: folds softmax's 1/ln2 so attn can use exp2 directly
          okb[base + (size_t)h * 16384 + d] = f2bf(acc[mi][nj][r] * 0.18033688f);
        }
      } else {
        #pragma unroll
        for (int nj = 0; nj < 4; nj++) {
          int col = n0 + wc * 64 + nj * 16 + lr;
          of[(size_t)row * 1024 + col] = acc[mi][nj][r];
        }
      }
    }
  }
}

// ---------------- v [bh][4352][64] -> vT [bh][64][4352] ----------------
__global__ void __launch_bounds__(256) vtrans_kernel(const ushort* __restrict__ v,
                                                     ushort* __restrict__ vt) {
  int bh = blockIdx.x / 68, tk = blockIdx.x - bh * 68;
  __shared__ ushort tl[64][65];
  int t = threadIdx.x;
  const ushort* src = v + (size_t)bh * 278528 + (size_t)tk * 4096;
  #pragma unroll
  for (int c2 = 0; c2 < 2; c2++) {
    int idx = t + c2 * 256;
    int row = idx >> 3, cb = idx & 7;
    i32x4 d4 = *(const i32x4*)(src + row * 64 + cb * 8);
    const ushort* p = (const ushort*)&d4;
    #pragma unroll
    for (int e = 0; e < 8; e++) tl[row][cb * 8 + e] = p[e];
  }
  __syncthreads();
  ushort* dst = vt + (size_t)bh * 278528 + tk * 64;
  #pragma unroll
  for (int i = 0; i < 16; i++) {
    int idx = t + i * 256;
    int d = idx >> 6, key = idx & 63;
    dst[(size_t)d * 4352 + key] = tl[key][d];
  }
}

// ---------------- flash attention: fixed-shift exp2 softmax + dbuf + counted vmcnt ----------------
// LDS 50.7KB -> 3 blocks/CU (12 waves). Bias stored bf16 (uniform-shift rounding cancels
// in normalization). Q pre-scaled by (1/8)/ln2 so exp2f is a bare v_exp_f32.
__global__ void __launch_bounds__(256, 3) attn_kernel(
    const ushort* __restrict__ qb, const ushort* __restrict__ kb,
    const ushort* __restrict__ vt, const int* __restrict__ mask,
    ushort* __restrict__ ao) {
  int orig = blockIdx.x;
  int bid = ((orig & 7) << 6) + (orig >> 3);   // grid 512 = 8 * 64
  int qt = bid & 3; int h = (bid >> 2) & 15; int b = bid >> 6;
  int t = threadIdx.x, w = t >> 6, l = t & 63, lg = l >> 4, lr = l & 15;
  __shared__ ushort Kl[2][4096];
  __shared__ ushort Vl[2][4096];
  __shared__ ushort Pl[64 * 72];
  __shared__ ushort biasb[4352];
  size_t bh = (size_t)b * 16 + h;
  const ushort* qhead = qb + bh * 16384 + (size_t)qt * 4096;
  const ushort* khead = kb + bh * 278528;
  const ushort* vthead = vt + bh * 278528;

  #pragma unroll
  for (int c2 = 0; c2 < 2; c2++) {
    int c = w * 2 + c2;
    int row = c * 8 + (l >> 3);
    int colb = ((l & 7) * 16) ^ ((row & 7) << 4);
    gload_lds16((const char*)qhead + row * 128 + colb, (char*)Kl + c * 1024);
  }
  // mask -> additive bias (log2 domain) with fixed shift -24/ln2 folded in
  for (int i = t; i < 4352; i += 256)
    biasb[i] = f2bf(mask[b * 4352 + i] ? -34.625f : -14462.0f);
  __syncthreads();
  i32x4 aq[2];
  #pragma unroll
  for (int kh = 0; kh < 2; kh++) {
    int row = w * 16 + lr;
    int off = (row * 128 + kh * 64 + lg * 16) ^ ((row & 7) << 4);
    aq[kh] = *(const i32x4*)((const char*)Kl + off);
  }
  __syncthreads();

  auto stage = [&](int tk, int bsel) {
    #pragma unroll
    for (int c2 = 0; c2 < 2; c2++) {
      int c = w * 2 + c2;
      int row = c * 8 + (l >> 3);
      int colb = ((l & 7) * 16) ^ ((row & 7) << 4);
      gload_lds16((const char*)khead + (size_t)(tk * 64 + row) * 128 + colb,
                  (char*)Kl + bsel * 8192 + c * 1024);
      gload_lds16((const char*)vthead + (size_t)row * 8704 + (size_t)tk * 128 + colb,
                  (char*)Vl + bsel * 8192 + c * 1024);
    }
  };

  float lsum[4];
  f32x4 oacc[4];
  #pragma unroll
  for (int r = 0; r < 4; r++) lsum[r] = 0.f;
  #pragma unroll
  for (int df = 0; df < 4; df++) oacc[df] = (f32x4){0.f, 0.f, 0.f, 0.f};

  stage(0, 0);
  int cur = 0;
  for (int tk = 0; tk < 68; tk++) {
    if (tk < 67) {
      stage(tk + 1, cur ^ 1);
      asm volatile("s_waitcnt vmcnt(4)" ::: "memory");
    } else {
      asm volatile("s_waitcnt vmcnt(0)" ::: "memory");
    }
    asm volatile("s_barrier" ::: "memory");
    const char* Kb = (const char*)Kl + cur * 8192;
    const char* Vb = (const char*)Vl + cur * 8192;

    // S = Q K^T  (log2-scaled logits)
    f32x4 sf[4];
    #pragma unroll
    for (int kf = 0; kf < 4; kf++) {
      f32x4 s = (f32x4){0.f, 0.f, 0.f, 0.f};
      #pragma unroll
      for (int kh = 0; kh < 2; kh++) {
        int row = kf * 16 + lr;
        int off = (row * 128 + kh * 64 + lg * 16) ^ ((row & 7) << 4);
        i32x4 bk = *(const i32x4*)(Kb + off);
        mfma_acc(s, aq[kh], bk);
      }
      sf[kf] = s;
    }
    // fixed-shift exp2: no max tracking, no rescale, deferred row-sum
    #pragma unroll
    for (int kf = 0; kf < 4; kf++) {
      float ma = bf2f(biasb[tk * 64 + kf * 16 + lr]);
      #pragma unroll
      for (int r = 0; r < 4; r++) {
        float p = exp2f(sf[kf][r] + ma);
        lsum[r] += p;
        Pl[(w * 16 + lg * 4 + r) * 72 + kf * 16 + lr] = f2bf(p);
      }
    }
    // O += P V
    #pragma unroll
    for (int kq = 0; kq < 2; kq++) {
      i32x4 ap = *(const i32x4*)&Pl[(w * 16 + lr) * 72 + kq * 32 + lg * 8];
      #pragma unroll
      for (int df = 0; df < 4; df++) {
        int row = df * 16 + lr;
        int off = (row * 128 + kq * 64 + lg * 16) ^ ((row & 7) << 4);
        i32x4 bv = *(const i32x4*)(Vb + off);
        mfma_acc(oacc[df], ap, bv);
      }
    }
    asm volatile("s_barrier" ::: "memory");
    cur ^= 1;
  }
  #pragma unroll
  for (int o = 1; o < 16; o <<= 1)
    #pragma unroll
    for (int r = 0; r < 4; r++) lsum[r] += __shfl_xor(lsum[r], o, 64);
  #pragma unroll
  for (int r = 0; r < 4; r++) lsum[r] = 1.f / lsum[r];
  int n2 = qt * 64 + w * 16 + lg * 4;
  #pragma unroll
  for (int df = 0; df < 4; df++)
    #pragma unroll
    for (int r = 0; r < 4; r++) {
      float vv = oacc[df][r] * lsum[r];
      ao[((size_t)b * 256 + (n2 + r)) * 1024 + h * 64 + df * 16 + lr] = f2bf(vv);
    }
}

extern "C" void kernel_launch(void* const* d_in, const int* in_sizes, int n_in,
                              void* d_out, int out_size, void* d_ws, size_t ws_size,
                              hipStream_t stream) {
  const float* x    = (const float*)d_in[0];
  const float* lat  = (const float*)d_in[1];
  const int*   msk  = (const int*)d_in[2];
  const float* gm   = (const float*)d_in[3];
  const float* bm   = (const float*)d_in[4];
  const float* gl   = (const float*)d_in[5];
  const float* bl   = (const float*)d_in[6];
  const float* Wq   = (const float*)d_in[7];
  const float* Wkv  = (const float*)d_in[8];
  const float* Wout = (const float*)d_in[9];
  float* out = (float*)d_out;
  char* ws = (char*)d_ws;

  ushort* xcat  = (ushort*)(ws);                    // 71,303,168 B (reused as vT later)
  ushort* kbuf  = (ushort*)(ws + 71303168);         // 71,303,168
  ushort* vbuf  = (ushort*)(ws + 142606336);        // 71,303,168
  ushort* qbuf  = (ushort*)(ws + 213909504);        //  4,194,304
  ushort* aobuf = (ushort*)(ws + 218103808);        //  4,194,304
  ushort* wkvt  = (ushort*)(ws + 222298112);        //  4,194,304
  ushort* wqt   = (ushort*)(ws + 226492416);        //  2,097,152
  ushort* wot   = (ushort*)(ws + 228589568);        //  2,097,152
  ushort* vt    = xcat;                             // alias: xcat dead after q-GEMM

  ln_kernel<<<34816, 256, 0, stream>>>(x, lat, gm, bm, gl, bl, xcat);
  tsplit3_kernel<<<2048, 256, 0, stream>>>(Wkv, Wq, Wout, wkvt, wqt, wot);
  gemm256_kv<<<1088, 512, 0, stream>>>(xcat, wkvt, kbuf, vbuf);
  gemm_nt<1><<<16 * 8, 256, 0, stream>>>(xcat, wqt, qbuf, nullptr, 8, 1024, 1024, 1024);
  vtrans_kernel<<<128 * 68, 256, 0, stream>>>(vbuf, vt);
  attn_kernel<<<512, 256, 0, stream>>>(qbuf, kbuf, vt, msk, aobuf);
  gemm_nt<2><<<16 * 8, 256, 0, stream>>>(aobuf, wot, nullptr, out, 8, 1024, 1024, 1024);
}

// Round 10
// 352.949 us; speedup vs baseline: 1.0649x; 1.0649x over previous
//
#include <hip/hip_runtime.h>
#include <stdint.h>

typedef __attribute__((ext_vector_type(4))) float f32x4;
typedef __attribute__((ext_vector_type(4))) int   i32x4;

__device__ __forceinline__ ushort f2bf(float f) {
  union { float f; uint32_t u; } v; v.f = f;
  uint32_t r = v.u + 0x7FFFu + ((v.u >> 16) & 1u);
  return (ushort)(r >> 16);
}
__device__ __forceinline__ void mfma_acc(f32x4& c, i32x4 a, i32x4 b) {
  asm volatile("v_mfma_f32_16x16x32_bf16 %0, %1, %2, %0" : "+v"(c) : "v"(a), "v"(b));
}
__device__ __forceinline__ void gload_lds16(const void* g, void* lds) {
  __builtin_amdgcn_global_load_lds(
      (const __attribute__((address_space(1))) void*)g,
      (__attribute__((address_space(3))) void*)lds, 16, 0, 0);
}

// ---------------- LN + bf16 cast, wave-per-row (no barriers, no LDS) ----------------
// block = 256 threads = 4 waves = 4 rows; row = blockIdx.x*4 + wave
__global__ void __launch_bounds__(256) ln_kernel(
    const float* __restrict__ x, const float* __restrict__ lat,
    const float* __restrict__ gm, const float* __restrict__ bm,
    const float* __restrict__ gl, const float* __restrict__ bl,
    ushort* __restrict__ out) {
  int t = threadIdx.x, w = t >> 6, l = t & 63;
  int row = blockIdx.x * 4 + w;
  int b = row / 4352, j = row - b * 4352;
  const float *src, *g, *bi;
  if (j < 4096) { src = x + ((size_t)b * 4096 + j) * 1024; g = gm; bi = bm; }
  else          { src = lat + ((size_t)b * 256 + (j - 4096)) * 1024; g = gl; bi = bl; }
  const f32x4* src4 = (const f32x4*)src;
  f32x4 v[4];
  float s = 0.f, q = 0.f;
  #pragma unroll
  for (int i = 0; i < 4; i++) {
    v[i] = src4[l + i * 64];
    s += v[i].x + v[i].y + v[i].z + v[i].w;
    q += v[i].x * v[i].x + v[i].y * v[i].y + v[i].z * v[i].z + v[i].w * v[i].w;
  }
  #pragma unroll
  for (int o = 1; o < 64; o <<= 1) { s += __shfl_xor(s, o, 64); q += __shfl_xor(q, o, 64); }
  float mu = s * (1.f / 1024.f);
  float var = q * (1.f / 1024.f) - mu * mu;
  float rs = rsqrtf(var + 1e-5f);
  ushort4* dst4 = (ushort4*)(out + (size_t)row * 1024);
  #pragma unroll
  for (int i = 0; i < 4; i++) {
    f32x4 gg = ((const f32x4*)g)[l + i * 64];
    f32x4 bb = ((const f32x4*)bi)[l + i * 64];
    ushort4 o4;
    o4.x = f2bf((v[i].x - mu) * rs * gg.x + bb.x);
    o4.y = f2bf((v[i].y - mu) * rs * gg.y + bb.y);
    o4.z = f2bf((v[i].z - mu) * rs * gg.z + bb.z);
    o4.w = f2bf((v[i].w - mu) * rs * gg.w + bb.w);
    dst4[l + i * 64] = o4;
  }
}

// ------------- merged weight transposes: Wkv, Wq, Wout -> [N][1024] bf16 -------------
__global__ void __launch_bounds__(256) tsplit3_kernel(
    const float* __restrict__ Wkv, const float* __restrict__ Wq, const float* __restrict__ Wout,
    ushort* __restrict__ wkvt, ushort* __restrict__ wqt, ushort* __restrict__ wot) {
  int bid = blockIdx.x;
  const float* W; ushort* out; int N, bid2;
  if (bid < 1024)      { W = Wkv;  out = wkvt; N = 2048; bid2 = bid; }
  else if (bid < 1536) { W = Wq;   out = wqt;  N = 1024; bid2 = bid - 1024; }
  else                 { W = Wout; out = wot;  N = 1024; bid2 = bid - 1536; }
  int ntn = N >> 6;
  int tk = bid2 / ntn, tn = bid2 - tk * ntn;
  int k0 = tk * 32, n0 = tn * 64;
  __shared__ float tile[32][65];
  int t = threadIdx.x;
  #pragma unroll
  for (int i = 0; i < 8; i++) {
    int idx = t + i * 256;              // 2048 = 32x64
    int k = idx >> 6, n = idx & 63;
    tile[k][n] = W[(size_t)(k0 + k) * N + n0 + n];
  }
  __syncthreads();
  #pragma unroll
  for (int i = 0; i < 8; i++) {
    int idx = t + i * 256;
    int n = idx >> 5, k = idx & 31;
    out[(size_t)(n0 + n) * 1024 + k0 + k] = f2bf(tile[k][n]);
  }
}

// ======= kv GEMM: 256x256, BK=64, 8 waves, 8-phase schedule (4 phases/K-tile) =======
// LDS: 2 slots x {A0,A1,B0,B1} half-tiles (16KB each; 128 rows x 64 bf16, row-XOR swizzle).
// Phase quadrants: P1=(M0,N0) P2=(M0,N1) P3=(M1,N1) P4=(M1,N0).
// Stages: P1: A1(T+1)->next slot; P2: B0(T+1)->next; P3: A0(T+2)->cur; P4: B1(T+2)->cur.
// Each half staged strictly after its last LDS read (barrier-separated). Boundary wait:
// vmcnt(4) once per K-tile; vmcnt(0) into the last two tiles.
__global__ void __launch_bounds__(512, 2) gemm256_kv(
    const ushort* __restrict__ A, const ushort* __restrict__ Bw,
    ushort* __restrict__ okb, ushort* __restrict__ ovb) {
  int orig = blockIdx.x;
  int bx = (orig & 7) * 136 + (orig >> 3);       // 1088 = 8 XCD * 136
  int mt = bx >> 3, nt = bx & 7;
  int m0 = mt * 256, n0 = nt * 256;
  int t = threadIdx.x, w = t >> 6, l = t & 63, lg = l >> 4, lr = l & 15;
  int wr = w >> 2, wc = w & 3;                   // 2 x 4 waves; wave subtile 64x32 per quadrant

  __shared__ char smem[131072];                  // slot s at s*65536: A0 +0, A1 +16K, B0 +32K, B1 +48K

  auto stageH = [&](const ushort* src, int rowbase, int h, int T, char* dst) {
    #pragma unroll
    for (int i = 0; i < 2; i++) {
      int c = t + i * 512;                       // 1024 chunks of 16B = 128 rows x 128B
      int rl = c >> 3, j = c & 7;
      int sj = j ^ (rl & 7);                     // pre-swizzled source (involution)
      gload_lds16(src + ((size_t)(rowbase + h * 128 + rl) * 1024 + (size_t)T * 64 + sj * 8),
                  dst + c * 16);
    }
  };

  f32x4 acc[4][4][2];
  #pragma unroll
  for (int p = 0; p < 4; p++)
    #pragma unroll
    for (int i = 0; i < 4; i++)
      #pragma unroll
      for (int j = 0; j < 2; j++) acc[p][i][j] = (f32x4){0.f, 0.f, 0.f, 0.f};

  // prologue: slot0 fully + A0(1), B1(1) into slot1
  stageH(A,  m0, 0, 0, smem);
  stageH(A,  m0, 1, 0, smem + 16384);
  stageH(Bw, n0, 0, 0, smem + 32768);
  stageH(Bw, n0, 1, 0, smem + 49152);
  stageH(A,  m0, 0, 1, smem + 65536);
  stageH(Bw, n0, 1, 1, smem + 65536 + 49152);
  asm volatile("s_waitcnt vmcnt(4)" ::: "memory");
  __builtin_amdgcn_s_barrier();

  const int arl = wr * 64 + lr;
  const int brl = wc * 32 + lr;
  const int kcol0 = lg * 16;

  for (int T = 0; T < 16; T++) {
    char* cs = smem + (T & 1) * 65536;
    char* ns = smem + ((T + 1) & 1) * 65536;
    i32x4 a[4][2], b[2][2];

    // ---- P1: quadrant (M0,N0): read A0 + B0, stage A1(T+1) ----
    #pragma unroll
    for (int mi = 0; mi < 4; mi++) {
      int rl = arl + mi * 16;
      #pragma unroll
      for (int kk = 0; kk < 2; kk++)
        a[mi][kk] = *(const i32x4*)(cs + rl * 128 + ((kk * 64 + kcol0) ^ ((rl & 7) << 4)));
    }
    #pragma unroll
    for (int nj = 0; nj < 2; nj++) {
      int rl = brl + nj * 16;
      #pragma unroll
      for (int kk = 0; kk < 2; kk++)
        b[nj][kk] = *(const i32x4*)(cs + 32768 + rl * 128 + ((kk * 64 + kcol0) ^ ((rl & 7) << 4)));
    }
    if (T + 1 < 16) stageH(A, m0, 1, T + 1, ns + 16384);
    __builtin_amdgcn_s_barrier();
    __builtin_amdgcn_s_setprio(1);
    #pragma unroll
    for (int mi = 0; mi < 4; mi++)
      #pragma unroll
      for (int nj = 0; nj < 2; nj++)
        #pragma unroll
        for (int kk = 0; kk < 2; kk++) mfma_acc(acc[0][mi][nj], a[mi][kk], b[nj][kk]);
    __builtin_amdgcn_s_setprio(0);
    __builtin_amdgcn_s_barrier();

    // ---- P2: quadrant (M0,N1): reuse a, read B1, stage B0(T+1) ----
    #pragma unroll
    for (int nj = 0; nj < 2; nj++) {
      int rl = brl + nj * 16;
      #pragma unroll
      for (int kk = 0; kk < 2; kk++)
        b[nj][kk] = *(const i32x4*)(cs + 49152 + rl * 128 + ((kk * 64 + kcol0) ^ ((rl & 7) << 4)));
    }
    if (T + 1 < 16) stageH(Bw, n0, 0, T + 1, ns + 32768);
    __builtin_amdgcn_s_barrier();
    __builtin_amdgcn_s_setprio(1);
    #pragma unroll
    for (int mi = 0; mi < 4; mi++)
      #pragma unroll
      for (int nj = 0; nj < 2; nj++)
        #pragma unroll
        for (int kk = 0; kk < 2; kk++) mfma_acc(acc[1][mi][nj], a[mi][kk], b[nj][kk]);
    __builtin_amdgcn_s_setprio(0);
    __builtin_amdgcn_s_barrier();

    // ---- P3: quadrant (M1,N1): read A1, reuse b, stage A0(T+2) into cur slot ----
    #pragma unroll
    for (int mi = 0; mi < 4; mi++) {
      int rl = arl + mi * 16;
      #pragma unroll
      for (int kk = 0; kk < 2; kk++)
        a[mi][kk] = *(const i32x4*)(cs + 16384 + rl * 128 + ((kk * 64 + kcol0) ^ ((rl & 7) << 4)));
    }
    if (T + 2 < 16) stageH(A, m0, 0, T + 2, cs);
    __builtin_amdgcn_s_barrier();
    __builtin_amdgcn_s_setprio(1);
    #pragma unroll
    for (int mi = 0; mi < 4; mi++)
      #pragma unroll
      for (int nj = 0; nj < 2; nj++)
        #pragma unroll
        for (int kk = 0; kk < 2; kk++) mfma_acc(acc[2][mi][nj], a[mi][kk], b[nj][kk]);
    __builtin_amdgcn_s_setprio(0);
    __builtin_amdgcn_s_barrier();

    // ---- P4: quadrant (M1,N0): reuse a, re-read B0, stage B1(T+2) into cur slot ----
    #pragma unroll
    for (int nj = 0; nj < 2; nj++) {
      int rl = brl + nj * 16;
      #pragma unroll
      for (int kk = 0; kk < 2; kk++)
        b[nj][kk] = *(const i32x4*)(cs + 32768 + rl * 128 + ((kk * 64 + kcol0) ^ ((rl & 7) << 4)));
    }
    if (T + 2 < 16) stageH(Bw, n0, 1, T + 2, cs + 49152);
    __builtin_amdgcn_s_barrier();
    __builtin_amdgcn_s_setprio(1);
    #pragma unroll
    for (int mi = 0; mi < 4; mi++)
      #pragma unroll
      for (int nj = 0; nj < 2; nj++)
        #pragma unroll
        for (int kk = 0; kk < 2; kk++) mfma_acc(acc[3][mi][nj], a[mi][kk], b[nj][kk]);
    __builtin_amdgcn_s_setprio(0);
    if (T < 14) asm volatile("s_waitcnt vmcnt(4)" ::: "memory");
    else        asm volatile("s_waitcnt vmcnt(0)" ::: "memory");
    __builtin_amdgcn_s_barrier();
  }

  // scatter epilogue: quadrant p -> rows qm*128, cols qn*128; k cols<1024 -> kbuf else vbuf
  const int qmt[4] = {0, 0, 1, 1};
  const int qnt[4] = {0, 1, 1, 0};
  #pragma unroll
  for (int p = 0; p < 4; p++) {
    #pragma unroll
    for (int mi = 0; mi < 4; mi++) {
      #pragma unroll
      for (int r = 0; r < 4; r++) {
        int row = m0 + qmt[p] * 128 + wr * 64 + mi * 16 + lg * 4 + r;
        int bb = row / 4352; int n = row - bb * 4352;
        size_t base = (size_t)bb * 4456448 + (size_t)n * 64;
        #pragma unroll
        for (int nj = 0; nj < 2; nj++) {
          int col = n0 + qnt[p] * 128 + wc * 32 + nj * 16 + lr;
          int cc = col & 1023; int h = cc >> 6; int d = cc & 63;
          ushort* dst = (col < 1024) ? okb : ovb;
          dst[base + (size_t)h * 278528 + d] = f2bf(acc[p][mi][nj][r]);
        }
      }
    }
  }
}

// ---------------- small NT GEMM 128x128xBK32 (q and out projections) ----------------
template<int MODE>
__global__ void __launch_bounds__(256, 2) gemm_nt(
    const ushort* __restrict__ A, const ushort* __restrict__ Bw,
    ushort* __restrict__ okb, float* __restrict__ of,
    int ntn, int Keff, int lda, int ldb) {
  int orig = blockIdx.x;
  int bx = ((orig & 7) * (gridDim.x >> 3)) + (orig >> 3);
  int m0 = (bx / ntn) * 128, n0 = (bx - (bx / ntn) * ntn) * 128;
  int t = threadIdx.x, w = t >> 6, l = t & 63, lg = l >> 4, lr = l & 15;
  int wr = w >> 1, wc = w & 1;
  __shared__ ushort As[128 * 32];
  __shared__ ushort Bs[128 * 32];
  f32x4 acc[4][4];
  #pragma unroll
  for (int i = 0; i < 4; i++)
    #pragma unroll
    for (int j = 0; j < 4; j++) acc[i][j] = (f32x4){0.f, 0.f, 0.f, 0.f};

  int nk = Keff >> 5;
  for (int kt = 0; kt < nk; kt++) {
    int ka = kt * 32;
    #pragma unroll
    for (int c2 = 0; c2 < 2; c2++) {
      int c = w * 2 + c2;
      int arow = m0 + c * 16 + (l >> 2);
      if (MODE == 1) arow = ((arow >> 8) * 4352) + 4096 + (arow & 255);
      gload_lds16(A + (size_t)arow * lda + ka + (l & 3) * 8, &As[c * 512]);
    }
    #pragma unroll
    for (int c2 = 0; c2 < 2; c2++) {
      int c = w * 2 + c2;
      int brow = n0 + c * 16 + (l >> 2);
      gload_lds16(Bw + (size_t)brow * ldb + ka + (l & 3) * 8, &Bs[c * 512]);
    }
    __syncthreads();
    i32x4 af[4], bf[4];
    #pragma unroll
    for (int mi = 0; mi < 4; mi++)
      af[mi] = *(const i32x4*)&As[(wr * 64 + mi * 16 + lr) * 32 + lg * 8];
    #pragma unroll
    for (int nj = 0; nj < 4; nj++)
      bf[nj] = *(const i32x4*)&Bs[(wc * 64 + nj * 16 + lr) * 32 + lg * 8];
    #pragma unroll
    for (int mi = 0; mi < 4; mi++)
      #pragma unroll
      for (int nj = 0; nj < 4; nj++) mfma_acc(acc[mi][nj], af[mi], bf[nj]);
    __syncthreads();
  }

  #pragma unroll
  for (int mi = 0; mi < 4; mi++) {
    #pragma unroll
    for (int r = 0; r < 4; r++) {
      int row = m0 + wr * 64 + mi * 16 + lg * 4 + r;
      if (MODE == 1) {
        int b = row >> 8; int n2 = row & 255;
        size_t base = (size_t)b * 262144 + (size_t)n2 * 64;
        #pragma unroll
        for (int nj = 0; nj < 4; nj++) {
          int col = n0 + wc * 64 + nj * 16 + lr;
          int h = col >> 6; int d = col & 63;
          okb[base + (size_t)h * 16384 + d] = f2bf(acc[mi][nj][r] * 0.125f);
        }
      } else {
        #pragma unroll
        for (int nj = 0; nj < 4; nj++) {
          int col = n0 + wc * 64 + nj * 16 + lr;
          of[(size_t)row * 1024 + col] = acc[mi][nj][r];
        }
      }
    }
  }
}

// ---------------- v [bh][4352][64] -> vT [bh][64][4352] ----------------
__global__ void __launch_bounds__(256) vtrans_kernel(const ushort* __restrict__ v,
                                                     ushort* __restrict__ vt) {
  int bh = blockIdx.x / 68, tk = blockIdx.x - bh * 68;
  __shared__ ushort tl[64][65];
  int t = threadIdx.x;
  const ushort* src = v + (size_t)bh * 278528 + (size_t)tk * 4096;
  #pragma unroll
  for (int c2 = 0; c2 < 2; c2++) {
    int idx = t + c2 * 256;
    int row = idx >> 3, cb = idx & 7;
    i32x4 d4 = *(const i32x4*)(src + row * 64 + cb * 8);
    const ushort* p = (const ushort*)&d4;
    #pragma unroll
    for (int e = 0; e < 8; e++) tl[row][cb * 8 + e] = p[e];
  }
  __syncthreads();
  ushort* dst = vt + (size_t)bh * 278528 + tk * 64;
  #pragma unroll
  for (int i = 0; i < 16; i++) {
    int idx = t + i * 256;
    int d = idx >> 6, key = idx & 63;
    dst[(size_t)d * 4352 + key] = tl[key][d];
  }
}

// ---------------- flash attention: fixed-shift softmax + dbuf + counted vmcnt (R8-exact) ----------------
__global__ void __launch_bounds__(256, 2) attn_kernel(
    const ushort* __restrict__ qb, const ushort* __restrict__ kb,
    const ushort* __restrict__ vt, const int* __restrict__ mask,
    ushort* __restrict__ ao) {
  int orig = blockIdx.x;
  int bid = ((orig & 7) << 6) + (orig >> 3);   // grid 512 = 8 * 64
  int qt = bid & 3; int h = (bid >> 2) & 15; int b = bid >> 6;
  int t = threadIdx.x, w = t >> 6, l = t & 63, lg = l >> 4, lr = l & 15;
  __shared__ ushort Kl[2][4096];
  __shared__ ushort Vl[2][4096];
  __shared__ ushort Pl[64 * 72];
  __shared__ float bias[4352];
  size_t bh = (size_t)b * 16 + h;
  const ushort* qhead = qb + bh * 16384 + (size_t)qt * 4096;
  const ushort* khead = kb + bh * 278528;
  const ushort* vthead = vt + bh * 278528;

  #pragma unroll
  for (int c2 = 0; c2 < 2; c2++) {
    int c = w * 2 + c2;
    int row = c * 8 + (l >> 3);
    int colb = ((l & 7) * 16) ^ ((row & 7) << 4);
    gload_lds16((const char*)qhead + row * 128 + colb, (char*)Kl + c * 1024);
  }
  // mask -> additive bias with fixed shift -24 folded in (softmax shift-invariant;
  // logits ~N(0,1), max < ~6, so exp(s-24) in [e^-30, e^-18]: no overflow, bf16-safe)
  for (int i = t; i < 4352; i += 256)
    bias[i] = mask[b * 4352 + i] ? -24.0f : -10024.0f;
  __syncthreads();
  i32x4 aq[2];
  #pragma unroll
  for (int kh = 0; kh < 2; kh++) {
    int row = w * 16 + lr;
    int off = (row * 128 + kh * 64 + lg * 16) ^ ((row & 7) << 4);
    aq[kh] = *(const i32x4*)((const char*)Kl + off);
  }
  __syncthreads();

  auto stage = [&](int tk, int bsel) {
    #pragma unroll
    for (int c2 = 0; c2 < 2; c2++) {
      int c = w * 2 + c2;
      int row = c * 8 + (l >> 3);
      int colb = ((l & 7) * 16) ^ ((row & 7) << 4);
      gload_lds16((const char*)khead + (size_t)(tk * 64 + row) * 128 + colb,
                  (char*)Kl + bsel * 8192 + c * 1024);
      gload_lds16((const char*)vthead + (size_t)row * 8704 + (size_t)tk * 128 + colb,
                  (char*)Vl + bsel * 8192 + c * 1024);
    }
  };

  float lsum[4];
  f32x4 oacc[4];
  #pragma unroll
  for (int r = 0; r < 4; r++) lsum[r] = 0.f;
  #pragma unroll
  for (int df = 0; df < 4; df++) oacc[df] = (f32x4){0.f, 0.f, 0.f, 0.f};

  stage(0, 0);
  int cur = 0;
  for (int tk = 0; tk < 68; tk++) {
    if (tk < 67) {
      stage(tk + 1, cur ^ 1);
      asm volatile("s_waitcnt vmcnt(4)" ::: "memory");
    } else {
      asm volatile("s_waitcnt vmcnt(0)" ::: "memory");
    }
    asm volatile("s_barrier" ::: "memory");
    const char* Kb = (const char*)Kl + cur * 8192;
    const char* Vb = (const char*)Vl + cur * 8192;

    // S = Q K^T
    f32x4 sf[4];
    #pragma unroll
    for (int kf = 0; kf < 4; kf++) {
      f32x4 s = (f32x4){0.f, 0.f, 0.f, 0.f};
      #pragma unroll
      for (int kh = 0; kh < 2; kh++) {
        int row = kf * 16 + lr;
        int off = (row * 128 + kh * 64 + lg * 16) ^ ((row & 7) << 4);
        i32x4 bk = *(const i32x4*)(Kb + off);
        mfma_acc(s, aq[kh], bk);
      }
      sf[kf] = s;
    }
    // fixed-shift exp: no max tracking, no rescale, deferred row-sum
    #pragma unroll
    for (int kf = 0; kf < 4; kf++) {
      float ma = bias[tk * 64 + kf * 16 + lr];
      #pragma unroll
      for (int r = 0; r < 4; r++) {
        float p = __expf(sf[kf][r] + ma);
        lsum[r] += p;
        Pl[(w * 16 + lg * 4 + r) * 72 + kf * 16 + lr] = f2bf(p);
      }
    }
    // O += P V
    #pragma unroll
    for (int kq = 0; kq < 2; kq++) {
      i32x4 ap = *(const i32x4*)&Pl[(w * 16 + lr) * 72 + kq * 32 + lg * 8];
      #pragma unroll
      for (int df = 0; df < 4; df++) {
        int row = df * 16 + lr;
        int off = (row * 128 + kq * 64 + lg * 16) ^ ((row & 7) << 4);
        i32x4 bv = *(const i32x4*)(Vb + off);
        mfma_acc(oacc[df], ap, bv);
      }
    }
    asm volatile("s_barrier" ::: "memory");
    cur ^= 1;
  }
  #pragma unroll
  for (int o = 1; o < 16; o <<= 1)
    #pragma unroll
    for (int r = 0; r < 4; r++) lsum[r] += __shfl_xor(lsum[r], o, 64);
  #pragma unroll
  for (int r = 0; r < 4; r++) lsum[r] = 1.f / lsum[r];
  int n2 = qt * 64 + w * 16 + lg * 4;
  #pragma unroll
  for (int df = 0; df < 4; df++)
    #pragma unroll
    for (int r = 0; r < 4; r++) {
      float vv = oacc[df][r] * lsum[r];
      ao[((size_t)b * 256 + (n2 + r)) * 1024 + h * 64 + df * 16 + lr] = f2bf(vv);
    }
}

extern "C" void kernel_launch(void* const* d_in, const int* in_sizes, int n_in,
                              void* d_out, int out_size, void* d_ws, size_t ws_size,
                              hipStream_t stream) {
  const float* x    = (const float*)d_in[0];
  const float* lat  = (const float*)d_in[1];
  const int*   msk  = (const int*)d_in[2];
  const float* gm   = (const float*)d_in[3];
  const float* bm   = (const float*)d_in[4];
  const float* gl   = (const float*)d_in[5];
  const float* bl   = (const float*)d_in[6];
  const float* Wq   = (const float*)d_in[7];
  const float* Wkv  = (const float*)d_in[8];
  const float* Wout = (const float*)d_in[9];
  float* out = (float*)d_out;
  char* ws = (char*)d_ws;

  ushort* xcat  = (ushort*)(ws);                    // 71,303,168 B (reused as vT later)
  ushort* kbuf  = (ushort*)(ws + 71303168);         // 71,303,168
  ushort* vbuf  = (ushort*)(ws + 142606336);        // 71,303,168
  ushort* qbuf  = (ushort*)(ws + 213909504);        //  4,194,304
  ushort* aobuf = (ushort*)(ws + 218103808);        //  4,194,304
  ushort* wkvt  = (ushort*)(ws + 222298112);        //  4,194,304
  ushort* wqt   = (ushort*)(ws + 226492416);        //  2,097,152
  ushort* wot   = (ushort*)(ws + 228589568);        //  2,097,152
  ushort* vt    = xcat;                             // alias: xcat dead after q-GEMM

  ln_kernel<<<8704, 256, 0, stream>>>(x, lat, gm, bm, gl, bl, xcat);
  tsplit3_kernel<<<2048, 256, 0, stream>>>(Wkv, Wq, Wout, wkvt, wqt, wot);
  gemm256_kv<<<1088, 512, 0, stream>>>(xcat, wkvt, kbuf, vbuf);
  gemm_nt<1><<<16 * 8, 256, 0, stream>>>(xcat, wqt, qbuf, nullptr, 8, 1024, 1024, 1024);
  vtrans_kernel<<<128 * 68, 256, 0, stream>>>(vbuf, vt);
  attn_kernel<<<512, 256, 0, stream>>>(qbuf, kbuf, vt, msk, aobuf);
  gemm_nt<2><<<16 * 8, 256, 0, stream>>>(aobuf, wot, nullptr, out, 8, 1024, 1024, 1024);
}